// Round 2
// baseline (338.188 us; speedup 1.0000x reference)
//
#include <hip/hip_runtime.h>

// Retrace loss: per-row backward recurrence in t-space:
//   Q_ret[T-1] = tQ[T-1]
//   Q_ret[t]   = A[t]*Q_ret[t+1] + B[t],  t = T-2 .. 0
//   A[t] = G*c[t+1],  B[t] = 100*r[t] + G*(eQ[t+1] - c[t+1]*tQ[t+1])
//   c[u] = exp(min(tpp[u]-bpp[u], 0))
// Solved as a SUFFIX scan of affine maps (shfl_down based), one block per row.
//
// R2 change: EPT 8 -> 4, BLOCK 512 -> 1024, thread windows ASCENDING with tid.
// Rationale: R0/R1 both plateaued at ~126us (3.2 TB/s logical) with idle VALU
// and occupancy-insensitivity -> not latency-bound; suspect the per-thread-
// contiguous layout (lanes 32-64B apart per load instruction, descending,
// half/quarter cache-line coverage per transaction) halves effective memory
// throughput. With EPT=4 each wave-load is 64 lanes x 16B fully covering 16
// consecutive lines ascending -- the exact pattern the 6.3 TB/s copy µbench
// uses. The scan becomes a suffix scan (combine from higher tid / higher wave).

#define NROWS 4096
#define TLEN  4096
#define BLOCK 1024
#define EPT   4
#define NWV   (BLOCK / 64)

__global__ __launch_bounds__(BLOCK) void retrace_main(
    const float* __restrict__ Q,
    const float* __restrict__ eQ,
    const float* __restrict__ tQ,
    const float* __restrict__ rw,
    const float* __restrict__ tpp,
    const float* __restrict__ bpp,
    double* __restrict__ partials)
{
    constexpr float G = 0.99f;
    __shared__ float sWA[NWV], sWB[NWV];
    __shared__ float sRed[NWV];

    const int tid  = threadIdx.x;
    const int lane = tid & 63;
    const int wv   = tid >> 6;
    const long long base = (long long)blockIdx.x * TLEN;
    // Thread tid owns t in [4*tid, 4*tid+4): ascending, contiguous float4.
    const int ua = EPT * tid;

    // ---- Prefetch: 6 float4 loads, canonical coalesced pattern ----
    // (lane l of each wave -> 16B at base + 16B*l, fully-covered lines).
    float4 Tv4, Pv4, Qt4, Ev4, Rv4, Qm4;
    Tv4 = *(const float4*)(tpp + base + ua);
    Pv4 = *(const float4*)(bpp + base + ua);
    Qt4 = *(const float4*)(tQ  + base + ua);
    Ev4 = *(const float4*)(eQ  + base + ua);
    Rv4 = *(const float4*)(rw  + base + ua);

    // Lane 63 needs thread tid+1's element 0 (index ua+4) for its k=3 map but
    // can't shfl_down across the wave boundary: scalar loads (L1/L2 hits).
    // Global-last thread (tid==BLOCK-1) holds the terminal map instead.
    const bool bnd = (lane == 63) && (tid != BLOCK - 1);
    float bt = 0.f, bp = 0.f, bq = 0.f, be = 0.f;
    if (bnd) {
        bt = tpp[base + ua + EPT];
        bp = bpp[base + ua + EPT];
        bq = tQ [base + ua + EPT];
        be = eQ [base + ua + EPT];
    }

    // Q consumed last (after the scan) -> issued last, stays in flight longest.
    Qm4 = *(const float4*)(Q + base + ua);

    __builtin_amdgcn_sched_barrier(0);   // keep all load issues above this point

    float tv[4] = {Tv4.x, Tv4.y, Tv4.z, Tv4.w};
    float pv[4] = {Pv4.x, Pv4.y, Pv4.z, Pv4.w};
    float qv[4] = {Qt4.x, Qt4.y, Qt4.z, Qt4.w};
    float ev[4] = {Ev4.x, Ev4.y, Ev4.z, Ev4.w};
    float rv[4] = {Rv4.x, Rv4.y, Rv4.z, Rv4.w};
    float qm[4] = {Qm4.x, Qm4.y, Qm4.z, Qm4.w};

    // ---- Build the 4 affine maps, k = t - 4*tid ----
    float Aa[4], Bb[4];
    #pragma unroll
    for (int k = 0; k < 3; ++k) {
        const float c  = __expf(fminf(tv[k+1] - pv[k+1], 0.0f));
        const float gc = G * c;
        const float f  = fmaf(-gc, qv[k+1], G * ev[k+1]);
        Aa[k] = gc;
        Bb[k] = fmaf(100.0f, rv[k], f);
    }
    // k = 3: t+1 = ua+4 lives in thread tid+1's element 0.
    {
        float t4 = __shfl_down(tv[0], 1, 64);
        float p4 = __shfl_down(pv[0], 1, 64);
        float q4 = __shfl_down(qv[0], 1, 64);
        float e4 = __shfl_down(ev[0], 1, 64);
        if (bnd) { t4 = bt; p4 = bp; q4 = bq; e4 = be; }
        if (tid == BLOCK - 1) {
            // t = T-1: Q_ret = tQ[T-1] exactly (A = 0 kills incoming state).
            Aa[3] = 0.0f;
            Bb[3] = qv[3];             // tQ[base + TLEN - 1]
        } else {
            const float c  = __expf(fminf(t4 - p4, 0.0f));
            const float gc = G * c;
            const float f  = fmaf(-gc, q4, G * e4);
            Aa[3] = gc;
            Bb[3] = fmaf(100.0f, rv[3], f);
        }
    }

    // ---- Local composite: f_{4t} o f_{4t+1} o f_{4t+2} o f_{4t+3} ----
    float Ac = 1.0f, Bc = 0.0f;
    #pragma unroll
    for (int k = 3; k >= 0; --k) {
        Bc = fmaf(Aa[k], Bc, Bb[k]);
        Ac = Aa[k] * Ac;
    }

    // ---- Wave-level inclusive SUFFIX scan (combine from higher lanes) ----
    float Ai = Ac, Bi = Bc;
    #pragma unroll
    for (int off = 1; off < 64; off <<= 1) {
        const float Ap = __shfl_down(Ai, off, 64);
        const float Bp = __shfl_down(Bi, off, 64);
        if (lane < 64 - off) {
            Bi = fmaf(Ai, Bp, Bi);     // S_l = S_l o S_{l+off}  (B first: uses old Ai)
            Ai = Ai * Ap;
        }
    }

    // ---- Cross-wave combine: wave composite = lane 0's inclusive suffix ----
    if (lane == 0) { sWA[wv] = Ai; sWB[wv] = Bi; }
    __syncthreads();
    // Incoming state for wave wv = composite of waves (NWV-1 .. wv+1) applied
    // to anything (the terminal map's A=0 in wave NWV-1 kills the seed).
    float Bp = 0.0f;
    #pragma unroll
    for (int j = NWV - 1; j >= 1; --j)
        if (j > wv) Bp = fmaf(sWA[j], Bp, sWB[j]);

    // Exclusive suffix within wave = inclusive of lane+1 (identity at lane 63).
    float Ae = __shfl_down(Ai, 1, 64);
    float Be = __shfl_down(Bi, 1, 64);
    if (lane == 63) { Ae = 1.0f; Be = 0.0f; }
    float y = fmaf(Ae, Bp, Be);        // y = Q_ret[4*tid + 4] entering this thread

    // ---- Apply maps (t descending) + accumulate squared error vs Q ----
    float acc = 0.0f;
    #pragma unroll
    for (int k = 3; k >= 0; --k) {
        y = fmaf(Aa[k], y, Bb[k]);     // y = Q_ret[4*tid + k]
        const float d = qm[k] - y;
        acc = fmaf(d, d, acc);
    }

    // ---- Block reduction: wave shuffle + tiny LDS combine ----
    #pragma unroll
    for (int off = 32; off > 0; off >>= 1)
        acc += __shfl_down(acc, off, 64);
    if (lane == 0) sRed[wv] = acc;
    __syncthreads();
    if (tid == 0) {
        float s = 0.0f;
        #pragma unroll
        for (int j = 0; j < NWV; ++j) s += sRed[j];
        partials[blockIdx.x] = (double)s;  // every block writes its slot -> poison-safe
    }
}

#define FBLOCK 1024

__global__ __launch_bounds__(FBLOCK) void retrace_finalize(
    const double* __restrict__ partials, float* __restrict__ out)
{
    __shared__ double sRed[FBLOCK / 64];
    double s = 0.0;
    #pragma unroll
    for (int i = 0; i < NROWS / FBLOCK; ++i)
        s += partials[threadIdx.x + i * FBLOCK];
    #pragma unroll
    for (int off = 32; off > 0; off >>= 1)
        s += __shfl_down(s, off, 64);
    if ((threadIdx.x & 63) == 0) sRed[threadIdx.x >> 6] = s;
    __syncthreads();
    if (threadIdx.x == 0) {
        double tot = 0.0;
        #pragma unroll
        for (int j = 0; j < FBLOCK / 64; ++j) tot += sRed[j];
        out[0] = (float)(tot / ((double)NROWS * (double)TLEN));
    }
}

extern "C" void kernel_launch(void* const* d_in, const int* in_sizes, int n_in,
                              void* d_out, int out_size, void* d_ws, size_t ws_size,
                              hipStream_t stream)
{
    // setup_inputs order: Q, expected_target_Q, target_Q, rewards,
    //                     target_policy_probs, behaviour_policy_probs
    const float* Q   = (const float*)d_in[0];
    const float* eQ  = (const float*)d_in[1];
    const float* tQ  = (const float*)d_in[2];
    const float* rw  = (const float*)d_in[3];
    const float* tpp = (const float*)d_in[4];
    const float* bpp = (const float*)d_in[5];
    double* partials = (double*)d_ws;       // 4096 doubles = 32 KB scratch

    retrace_main<<<NROWS, BLOCK, 0, stream>>>(Q, eQ, tQ, rw, tpp, bpp, partials);
    retrace_finalize<<<1, FBLOCK, 0, stream>>>(partials, (float*)d_out);
}